// Round 15
// baseline (49.828 us; speedup 1.0000x reference)
//
#include <hip/hip_runtime.h>
#include <hip/hip_bf16.h>

typedef __attribute__((ext_vector_type(8))) short short8;
typedef __attribute__((ext_vector_type(4))) float floatx4;

#define B_ROWS 8192
#define DIM 128
#define NPAIR 4095
// rows scaled by sqrt(log2(e)) so S_mfma = S * log2(e) and exp(S) = exp2(S_mfma)
#define RSCALE 1.2011224087864498f

// force register materialization at this program point (defeats load sinking)
#define PIN(x) asm volatile("" : "+v"(x))

// ---------------- zero Z (fallback path only) ----------------
__global__ void kzero(float* __restrict__ Z) {
    int i = blockIdx.x * 256 + threadIdx.x;
    if (i < B_ROWS) Z[i] = 0.f;
}

// ------------- prep: normalize rows -> bf16 (scaled), exact fp32 pair dots -------------
// 1024 blocks x 256 thr; wave W: rows 2W (lanes 0-31), 2W+1 (lanes 32-63), float4/lane.
__global__ void kprep(const float* __restrict__ X, __hip_bfloat16* __restrict__ XN,
                      float* __restrict__ pairT, float* __restrict__ out) {
    const int wid = threadIdx.x >> 6;
    const int lane = threadIdx.x & 63;
    const int j = lane & 31;
    const int W = blockIdx.x * 4 + wid;  // wave index == pair index
    const int row = 2 * W + (lane >> 5);

    const float4 v = *reinterpret_cast<const float4*>(X + row * DIM + j * 4);
    float ss = v.x * v.x + v.y * v.y + v.z * v.z + v.w * v.w;
    #pragma unroll
    for (int m = 1; m < 32; m <<= 1) ss += __shfl_xor(ss, m, 64);  // within half
    const float rn = ss > 0.f ? rsqrtf(ss) : 0.f;

    // exact pair similarity via cross-half shuffle
    float4 pv;
    pv.x = __shfl_xor(v.x, 32, 64);
    pv.y = __shfl_xor(v.y, 32, 64);
    pv.z = __shfl_xor(v.z, 32, 64);
    pv.w = __shfl_xor(v.w, 32, 64);
    float pd = v.x * pv.x + v.y * pv.y + v.z * pv.z + v.w * pv.w;
    #pragma unroll
    for (int m = 1; m < 32; m <<= 1) pd += __shfl_xor(pd, m, 64);
    const float rno = __shfl_xor(rn, 32, 64);
    if (lane == 0 && W < NPAIR) pairT[W] = pd * rn * rno;

    // bf16 write (scaled)
    const float sc = rn * RSCALE;
    __hip_bfloat162 h0 = __float22bfloat162_rn(make_float2(v.x * sc, v.y * sc));
    __hip_bfloat162 h1 = __float22bfloat162_rn(make_float2(v.z * sc, v.w * sc));
    struct B4 { __hip_bfloat162 a, b; };
    *reinterpret_cast<B4*>(XN + row * DIM + j * 4) = B4{h0, h1};

    if (W == 0 && lane == 0) out[0] = 0.f;
}

// ------------- main: barrier-free wave-private GEMM, register B pipeline -------------
// grid (8, 64): y = row panel rb (128 rows), x = col group g (8 tiles of 128 cols).
// 4 waves 2x2 (wr, wc): wave owns 64 rows x 64 cols per tile, processed as two
// 32-col halves with ping-pong register B buffers. No LDS, no barriers: waves run
// free; prefetch pinned live via inline-asm so loads stay in flight under compute.
template <bool USEP>
__global__ void __launch_bounds__(256, 2) kgemm(const __hip_bfloat16* __restrict__ XN,
                                                float* __restrict__ ZP) {
    const int wid = threadIdx.x >> 6;
    const int lane = threadIdx.x & 63;
    const int lr = lane & 15;
    const int lk = lane >> 4;
    const int wr = wid >> 1;
    const int wc = wid & 1;
    const int rb = blockIdx.y;
    const int g = blockIdx.x;

    // ---- A: 64 rows in registers: a[kk][m], rows rb*128 + wr*64 + m*16 + lr ----
    short8 a[4][4];
    const __hip_bfloat16* Abase = XN + (rb * 128 + wr * 64 + lr) * DIM + lk * 8;
    #pragma unroll
    for (int m = 0; m < 4; ++m)
        #pragma unroll
        for (int kk = 0; kk < 4; ++kk)
            a[kk][m] = *reinterpret_cast<const short8*>(Abase + m * 16 * DIM + kk * 32);

    float rp[4][4];
    #pragma unroll
    for (int m = 0; m < 4; ++m)
        #pragma unroll
        for (int r = 0; r < 4; ++r) rp[m][r] = 0.f;

    const floatx4 zero4 = {0.f, 0.f, 0.f, 0.f};

    // wave's col-slice base: col = (g*8 + j)*128 + wc*64 + h*32 + n*16 + lr
    const __hip_bfloat16* Bcol = XN + (size_t)(wc * 64 + lr) * DIM + lk * 8;

    short8 bA[4][2], bB[4][2];

    // prologue: (tile 0, half 0) -> bA, pinned
    {
        const __hip_bfloat16* Bj = Bcol + (size_t)(g * 8) * 128 * DIM;
        #pragma unroll
        for (int n = 0; n < 2; ++n)
            #pragma unroll
            for (int kk = 0; kk < 4; ++kk) {
                bA[kk][n] = *reinterpret_cast<const short8*>(Bj + (n * 16) * DIM + kk * 32);
                PIN(bA[kk][n]);
            }
    }

    for (int j = 0; j < 8; ++j) {
        const int cbj = g * 8 + j;
        const __hip_bfloat16* Bj = Bcol + (size_t)cbj * 128 * DIM;
        const bool dtile = (cbj == rb) && (wr == wc);

        // issue half-1 loads, pin live (overlap half-0 compute)
        #pragma unroll
        for (int n = 0; n < 2; ++n)
            #pragma unroll
            for (int kk = 0; kk < 4; ++kk) {
                bB[kk][n] = *reinterpret_cast<const short8*>(Bj + (32 + n * 16) * DIM + kk * 32);
                PIN(bB[kk][n]);
            }

        // ---- half 0 (bA) ----
        floatx4 acc[4][2];
        #pragma unroll
        for (int m = 0; m < 4; ++m)
            #pragma unroll
            for (int n = 0; n < 2; ++n)
                acc[m][n] = __builtin_amdgcn_mfma_f32_16x16x32_bf16(a[0][m], bA[0][n], zero4, 0, 0, 0);
        #pragma unroll
        for (int kk = 1; kk < 4; ++kk)
            #pragma unroll
            for (int m = 0; m < 4; ++m)
                #pragma unroll
                for (int n = 0; n < 2; ++n)
                    acc[m][n] = __builtin_amdgcn_mfma_f32_16x16x32_bf16(a[kk][m], bA[kk][n], acc[m][n], 0, 0, 0);

        if (dtile) {
            #pragma unroll
            for (int m = 0; m < 4; ++m)
                #pragma unroll
                for (int n = 0; n < 2; ++n)
                    #pragma unroll
                    for (int r = 0; r < 4; ++r) {
                        float e = __builtin_amdgcn_exp2f(acc[m][n][r]);
                        if (m * 16 + lk * 4 + r == n * 16 + lr) e = 0.f;
                        rp[m][r] += e;
                    }
        } else {
            #pragma unroll
            for (int m = 0; m < 4; ++m)
                #pragma unroll
                for (int n = 0; n < 2; ++n)
                    #pragma unroll
                    for (int r = 0; r < 4; ++r)
                        rp[m][r] += __builtin_amdgcn_exp2f(acc[m][n][r]);
        }

        // issue next tile's half-0 loads, pin live (overlap half-1 compute)
        if (j < 7) {
            const __hip_bfloat16* Bn = Bcol + (size_t)(cbj + 1) * 128 * DIM;
            #pragma unroll
            for (int n = 0; n < 2; ++n)
                #pragma unroll
                for (int kk = 0; kk < 4; ++kk) {
                    bA[kk][n] = *reinterpret_cast<const short8*>(Bn + (n * 16) * DIM + kk * 32);
                    PIN(bA[kk][n]);
                }
        }

        // ---- half 1 (bB) ----
        #pragma unroll
        for (int m = 0; m < 4; ++m)
            #pragma unroll
            for (int n = 0; n < 2; ++n)
                acc[m][n] = __builtin_amdgcn_mfma_f32_16x16x32_bf16(a[0][m], bB[0][n], zero4, 0, 0, 0);
        #pragma unroll
        for (int kk = 1; kk < 4; ++kk)
            #pragma unroll
            for (int m = 0; m < 4; ++m)
                #pragma unroll
                for (int n = 0; n < 2; ++n)
                    acc[m][n] = __builtin_amdgcn_mfma_f32_16x16x32_bf16(a[kk][m], bB[kk][n], acc[m][n], 0, 0, 0);

        if (dtile) {
            #pragma unroll
            for (int m = 0; m < 4; ++m)
                #pragma unroll
                for (int n = 0; n < 2; ++n)
                    #pragma unroll
                    for (int r = 0; r < 4; ++r) {
                        float e = __builtin_amdgcn_exp2f(acc[m][n][r]);
                        if (m * 16 + lk * 4 + r == 32 + n * 16 + lr) e = 0.f;
                        rp[m][r] += e;
                    }
        } else {
            #pragma unroll
            for (int m = 0; m < 4; ++m)
                #pragma unroll
                for (int n = 0; n < 2; ++n)
                    #pragma unroll
                    for (int r = 0; r < 4; ++r)
                        rp[m][r] += __builtin_amdgcn_exp2f(acc[m][n][r]);
        }
    }

    // ---- row sums: reduce over lr, store P[row][slot] (transposed layout) ----
    #pragma unroll
    for (int m = 0; m < 4; ++m)
        #pragma unroll
        for (int r = 0; r < 4; ++r) {
            float v = rp[m][r];
            v += __shfl_xor(v, 1, 64);
            v += __shfl_xor(v, 2, 64);
            v += __shfl_xor(v, 4, 64);
            v += __shfl_xor(v, 8, 64);
            if (lr == 0) {
                const int row = rb * 128 + wr * 64 + m * 16 + lk * 4 + r;
                if (USEP)
                    ZP[row * 16 + (g * 2 + wc)] = v;
                else
                    atomicAdd(&ZP[row], v);
            }
        }
}

// ------------- final (P path): Z[r] = sum_16 P[r][slot] (contiguous); loss reduce -------------
__global__ void kfinalP(const float* __restrict__ P, const float* __restrict__ pairT,
                        float* __restrict__ out) {
    const int r = blockIdx.x * 256 + threadIdx.x;
    float s = 0.f;
    if (r < B_ROWS - 2) {
        const float4* p4 = reinterpret_cast<const float4*>(P + r * 16);
        float z = 0.f;
        #pragma unroll
        for (int i = 0; i < 4; ++i) {
            const float4 v = p4[i];
            z += v.x + v.y + v.z + v.w;
        }
        s = logf(z);
    }
    if (r < NPAIR) s -= 2.f * pairT[r];
    #pragma unroll
    for (int m = 1; m < 64; m <<= 1) s += __shfl_xor(s, m, 64);
    __shared__ float red[4];
    const int wid = threadIdx.x >> 6;
    const int lane = threadIdx.x & 63;
    if (lane == 0) red[wid] = s;
    __syncthreads();
    if (threadIdx.x == 0) {
        float tsum = red[0] + red[1] + red[2] + red[3];
        atomicAdd(out, tsum / (float)B_ROWS);
    }
}

// ------------- final (Z fallback path) -------------
__global__ void kfinalZ(const float* __restrict__ Z, const float* __restrict__ pairT,
                        float* __restrict__ out) {
    float s = 0.f;
    for (int r = threadIdx.x; r < B_ROWS - 2; r += 1024) s += logf(Z[r]);
    for (int p = threadIdx.x; p < NPAIR; p += 1024) s -= 2.f * pairT[p];
    #pragma unroll
    for (int m = 1; m < 64; m <<= 1) s += __shfl_xor(s, m, 64);
    __shared__ float red[16];
    const int wid = threadIdx.x >> 6;
    const int lane = threadIdx.x & 63;
    if (lane == 0) red[wid] = s;
    __syncthreads();
    if (threadIdx.x == 0) {
        float t = 0.f;
        #pragma unroll
        for (int i = 0; i < 16; ++i) t += red[i];
        out[0] = t / (float)B_ROWS;
    }
}

extern "C" void kernel_launch(void* const* d_in, const int* in_sizes, int n_in,
                              void* d_out, int out_size, void* d_ws, size_t ws_size,
                              hipStream_t stream) {
    (void)in_sizes; (void)n_in; (void)out_size;
    const float* X = (const float*)d_in[0];
    float* out = (float*)d_out;
    char* ws = (char*)d_ws;

    float* Z = (float*)ws;                                   // 32 KB (fallback)
    float* pairT = (float*)(ws + 32768);                     // 16 KB
    __hip_bfloat16* XN = (__hip_bfloat16*)(ws + 49152);      // 2 MB
    float* P = (float*)(ws + 49152 + 2097152);               // 512 KB (8192 x 16 f32)
    const size_t need = 49152 + 2097152 + (size_t)16 * B_ROWS * 4;
    const bool useP = ws_size >= need;

    kprep<<<1024, 256, 0, stream>>>(X, XN, pairT, out);
    if (useP) {
        kgemm<true><<<dim3(8, 64), 256, 0, stream>>>(XN, P);
        kfinalP<<<32, 256, 0, stream>>>(P, pairT, out);
    } else {
        kzero<<<32, 256, 0, stream>>>(Z);
        kgemm<false><<<dim3(8, 64), 256, 0, stream>>>(XN, Z);
        kfinalZ<<<1, 1024, 0, stream>>>(Z, pairT, out);
    }
}